// Round 3
// baseline (1701.239 us; speedup 1.0000x reference)
//
#include <hip/hip_runtime.h>
#include <cmath>

#define NB 8
#define NT 2048
#define NV 4096
#define NK 12          // top-K p values kept per row (candidate margin over 8)
#define CHUNK 128      // beam kernel: P/I rows staged in LDS per burst

__device__ __forceinline__ void lds_fence() {
  asm volatile("s_waitcnt lgkmcnt(0)" ::: "memory");
}

// ---------------------------------------------------------------------------
// Kernel A v3: whole 4096-wide row held in 64 VGPRs per lane (16 float4) ->
// exactly ONE HBM read + ONE HBM write (was 3 passes re-fetching ~1.5 GB).
// M = exact f32 row max; L = logf(f32 sum of __expf(x-M), 4 partials)
// (token path is invariant to per-row common-mode M/L perturbation; the
// ~1e-6 L deviation is the same order as the already-tolerated f64-vs-jax
// drift). logP = (x - M) - L. Top-12 (value desc, idx asc) unchanged.
// ---------------------------------------------------------------------------
__global__ __launch_bounds__(64) void lsm_top12_kernel(
    const float* __restrict__ logits,
    float* __restrict__ out_logP,
    float* __restrict__ topPf,
    int* __restrict__ topI)
{
  const int row  = blockIdx.x;           // b*NT + t
  const int lane = threadIdx.x;          // 0..63
  const float4* __restrict__ x4 = (const float4*)(logits + (size_t)row * NV);

  // ---- single HBM read: 16 independent dwordx4 loads into registers ----
  float4 r[16];
  #pragma unroll
  for (int k = 0; k < 16; ++k) r[k] = x4[lane + (k << 6)];

  // ---- exact f32 row max ----
  float m = -INFINITY;
  #pragma unroll
  for (int k = 0; k < 16; ++k)
    m = fmaxf(m, fmaxf(fmaxf(r[k].x, r[k].y), fmaxf(r[k].z, r[k].w)));
  #pragma unroll
  for (int off = 32; off > 0; off >>= 1) m = fmaxf(m, __shfl_xor(m, off, 64));

  // ---- f32 sum of exp, 4 partials; xor-butterfly keeps bits identical ----
  float a0 = 0.0f, a1 = 0.0f, a2 = 0.0f, a3 = 0.0f;
  #pragma unroll
  for (int k = 0; k < 16; ++k) {
    a0 += __expf(r[k].x - m);
    a1 += __expf(r[k].y - m);
    a2 += __expf(r[k].z - m);
    a3 += __expf(r[k].w - m);
  }
  float accf = (a0 + a1) + (a2 + a3);
  #pragma unroll
  for (int off = 32; off > 0; off >>= 1) accf += __shfl_xor(accf, off, 64);
  const float L32 = logf(accf);

  // ---- logP from registers + store + lane-local top-12 ----
  float lv[NK]; int li[NK];
  #pragma unroll
  for (int z = 0; z < NK; ++z) { lv[z] = -INFINITY; li[z] = 0x7FFFFFFF; }

  // strict > on value keeps earlier (lower) index among equals => stable
#define INS(VAL, IDX)                                                       \
  do {                                                                      \
    float _v = (VAL); int _i = (IDX);                                       \
    if (_v > lv[NK - 1]) {                                                  \
      lv[NK - 1] = _v; li[NK - 1] = _i;                                     \
      for (int z = NK - 1; z > 0; --z)                                      \
        if (lv[z] > lv[z - 1]) {                                            \
          float tv = lv[z]; lv[z] = lv[z - 1]; lv[z - 1] = tv;              \
          int   ti = li[z]; li[z] = li[z - 1]; li[z - 1] = ti;              \
        }                                                                   \
    }                                                                       \
  } while (0)

  float4* __restrict__ orow4 = (float4*)(out_logP + (size_t)row * NV);
  #pragma unroll
  for (int k = 0; k < 16; ++k) {
    const int vb = (lane + (k << 6)) << 2;
    float4 o;
    o.x = (r[k].x - m) - L32;
    o.y = (r[k].y - m) - L32;
    o.z = (r[k].z - m) - L32;
    o.w = (r[k].w - m) - L32;
    orow4[lane + (k << 6)] = o;
    INS(o.x, vb); INS(o.y, vb + 1); INS(o.z, vb + 2); INS(o.w, vb + 3);
  }
#undef INS

  // ---- wave merge: 12 rounds of butterfly argmax (value desc, idx asc) ----
  float mv = 0.0f; int mi = 0;
  #pragma unroll
  for (int rr = 0; rr < NK; ++rr) {
    float cv = lv[0]; int ci = li[0];
    #pragma unroll
    for (int off = 32; off > 0; off >>= 1) {
      float ov = __shfl_xor(cv, off, 64);
      int   oi = __shfl_xor(ci, off, 64);
      if (ov > cv || (ov == cv && oi < ci)) { cv = ov; ci = oi; }
    }
    if (rr == 0)    { mv = cv; mi = ci; }
    if (lane == rr) { mv = cv; mi = ci; }
    if (lv[0] == cv && li[0] == ci) {   // unique owner pops its head
      for (int z = 0; z < NK - 1; ++z) { lv[z] = lv[z + 1]; li[z] = li[z + 1]; }
      lv[NK - 1] = -INFINITY; li[NK - 1] = 0x7FFFFFFF;
    }
  }
  if (lane < NK) {
    topPf[(size_t)row * NK + lane] = mv;
    topI [(size_t)row * NK + lane] = mi;
  }
}

// ---------------------------------------------------------------------------
// Kernel B v4: f32 beam search + backtrace + CTC collapse. One wave per batch.
// 31 active lanes hold candidates (i,j) with (i+1)(j+1) <= 12 (margin kept:
// protects against late-t rounding-collision tie anomalies).
// v4: P/I rows staged into LDS in 128-row bursts (one vmcnt drain per 128
//     steps, ~7cy/step amortized) -> kills the per-step remote-L2 latency;
//     per-step operands via depth-1 LDS register prefetch (~60cy, hidden).
//     STEP selection math byte-identical to the verified v3.
// ---------------------------------------------------------------------------

// One beam step at time T. Chain: s -> cand -> key -> rank(31 readlane cmps)
// -> permute -> readlane x8 -> 3-level select -> s. Keys are unique (flat
// unique per active lane), so ranks are unique and lanes 0..7 of `pushed`
// hold the sorted top-8 candidate scores.
#define STEP(T, PV, VV)                                                       \
  do {                                                                        \
    const float cand = s + (PV);            /* single f32 add, matches np */  \
    unsigned int cb = __float_as_uint(cand);                                  \
    cb ^= (unsigned int)((int)cb >> 31) | 0x80000000u;                        \
    const unsigned int flat = (unsigned int)((i_l << 12) | (VV));             \
    const unsigned long long key =                                            \
        ((unsigned long long)cb << 15) | (unsigned long long)(0x7FFFu ^ flat);\
    const unsigned int klo = (unsigned int)key;                               \
    const unsigned int khi = (unsigned int)(key >> 32);                       \
    int rank = 0;                                                             \
    _Pragma("unroll")                                                         \
    for (int mm = 0; mm < 31; ++mm) {                                         \
      const unsigned int olo =                                                \
          (unsigned int)__builtin_amdgcn_readlane((int)klo, mm);              \
      const unsigned int ohi =                                                \
          (unsigned int)__builtin_amdgcn_readlane((int)khi, mm);              \
      const unsigned long long ok = ((unsigned long long)ohi << 32) | olo;    \
      rank += (ok > key) ? 1 : 0;                                             \
    }                                                                         \
    const bool win = active && (rank < 8);                                    \
    const int sloti = win ? ((T) * 8 + rank) : (NT * 8 + lane);               \
    tokbp[sloti] = (unsigned short)(((VV) << 3) | i_l);                       \
    const int dst4 = win ? (rank << 2) : park4;                               \
    const int pushed =                                                        \
        __builtin_amdgcn_ds_permute(dst4, __float_as_int(cand));              \
    const float w0 = __uint_as_float((unsigned)__builtin_amdgcn_readlane(pushed, 0)); \
    const float w1 = __uint_as_float((unsigned)__builtin_amdgcn_readlane(pushed, 1)); \
    const float w2 = __uint_as_float((unsigned)__builtin_amdgcn_readlane(pushed, 2)); \
    const float w3 = __uint_as_float((unsigned)__builtin_amdgcn_readlane(pushed, 3)); \
    const float w4 = __uint_as_float((unsigned)__builtin_amdgcn_readlane(pushed, 4)); \
    const float w5 = __uint_as_float((unsigned)__builtin_amdgcn_readlane(pushed, 5)); \
    const float w6 = __uint_as_float((unsigned)__builtin_amdgcn_readlane(pushed, 6)); \
    const float w7 = __uint_as_float((unsigned)__builtin_amdgcn_readlane(pushed, 7)); \
    const float sA_ = b0 ? w1 : w0;                                           \
    const float sB_ = b0 ? w3 : w2;                                           \
    const float sC_ = b0 ? w5 : w4;                                           \
    const float sD_ = b0 ? w7 : w6;                                           \
    const float sE_ = b1 ? sB_ : sA_;                                         \
    const float sF_ = b1 ? sD_ : sC_;                                         \
    s = b2 ? sF_ : sE_;                                                       \
  } while (0)

__global__ __launch_bounds__(64) void beam_kernel(
    const float* __restrict__ topPf,
    const int* __restrict__ topI,
    const int* __restrict__ lengths,
    float* __restrict__ out_tok,
    float* __restrict__ out_lenA,
    float* __restrict__ out_scr)
{
  const int b    = blockIdx.x;
  const int lane = threadIdx.x;

  __shared__ unsigned short tokbp[NT * 8 + 64]; // (v<<3)|bp per (t,rank) + dummy
  __shared__ unsigned short pathA[NT];
  __shared__ float pbuf[CHUNK][NK];             // 6 KiB staged P rows
  __shared__ int   ibuf[CHUNK][NK];             // 6 KiB staged I rows

  int len = lengths[b];
  if (len < 1) len = 1;
  if (len > NT) len = NT;

  // lane -> (i,j) over all (i+1)(j+1) <= 12  (counts 12,6,4,3,2,2,1,1 = 31)
  int i_l = 0, j_l = 0; bool active = false;
  {
    int c = 0;
    #pragma unroll
    for (int i = 0; i < 8; ++i) {
      const int cnt = 12 / (i + 1);          // floor
      if (lane >= c && lane < c + cnt) { i_l = i; j_l = lane - c; active = true; }
      c += cnt;
    }
  }
  const bool b0 = (i_l & 1) != 0;
  const bool b1 = (i_l & 2) != 0;
  const bool b2 = (i_l & 4) != 0;
  const int  park4 = (32 + (lane & 31)) << 2;   // loser/idle permute dst (bytes)

  const float* __restrict__ Pb = topPf + (size_t)b * NT * NK;
  const int*   __restrict__ Ib = topI  + (size_t)b * NT * NK;

  // t = 0: beams = row-0 top-8 (sorted desc, idx-asc ties)
  float s = Pb[i_l];
  if (lane < 8) tokbp[lane] = (unsigned short)(Ib[lane] << 3);   // bp = 0

  // ---- chunked main loop: burst-copy 128 rows of P/I to LDS, then step ----
  int t = 1;
  while (t < len) {
    const int t0   = t;
    const int tend = (t0 + CHUNK < len) ? (t0 + CHUNK) : len;
    const int n4   = (tend - t0) * 3;          // NK=12 floats -> 3 float4/row

    {
      const float4* __restrict__ gp = (const float4*)(Pb + (size_t)t0 * NK);
      const int4*   __restrict__ gi = (const int4*)(Ib + (size_t)t0 * NK);
      float4* __restrict__ lp = (float4*)&pbuf[0][0];
      int4*   __restrict__ lq = (int4*)&ibuf[0][0];
      for (int q = lane; q < n4; q += 64) { lp[q] = gp[q]; lq[q] = gi[q]; }
    }
    // single wave: compiler orders ds_write -> ds_read via lgkmcnt.

    float pc = pbuf[0][j_l];
    int   vc = ibuf[0][j_l];
    for (; t < tend; ++t) {
      const int ni = (t + 1 < tend) ? (t + 1 - t0) : (t - t0);
      const float pn = pbuf[ni][j_l];          // depth-1 LDS prefetch
      const int   vn = ibuf[ni][j_l];
      STEP(t, pc, vc);
      pc = pn; vc = vn;
    }
  }

  // ---- backtrace best beam (beam 0), b128 row loads staged 4 deep ----
  lds_fence();
  if (lane == 0) {
    const uint4* __restrict__ rows = (const uint4*)tokbp;  // 8 u16 per row
#define EXT(R)                                                                \
    do {                                                                      \
      const unsigned long long half = (beam < 4)                              \
          ? (((unsigned long long)(R).y << 32) | (R).x)                       \
          : (((unsigned long long)(R).w << 32) | (R).z);                      \
      const int e = (int)((half >> ((beam & 3) << 4)) & 0xFFFFu);             \
      pathA[bt] = (unsigned short)(e >> 3);                                   \
      beam = e & 7;                                                           \
      --bt;                                                                   \
    } while (0)
    int beam = 0;
    int bt = len - 1;
    uint4 r0 = rows[bt];
    uint4 r1 = rows[bt >= 1 ? bt - 1 : 0];
    uint4 r2 = rows[bt >= 2 ? bt - 2 : 0];
    uint4 r3 = rows[bt >= 3 ? bt - 3 : 0];
    while (bt >= 7) {
      const uint4 n0 = rows[bt - 4], n1 = rows[bt - 5];
      const uint4 n2 = rows[bt - 6], n3 = rows[bt - 7];
      EXT(r0); EXT(r1); EXT(r2); EXT(r3);
      r0 = n0; r1 = n1; r2 = n2; r3 = n3;
    }
    while (bt >= 0) { const uint4 rr = rows[bt]; EXT(rr); }
#undef EXT
  }
  lds_fence();

  // ---- CTC collapse: drop blanks & consecutive repeats, t < len ----
  const int CH = NT / 64;          // 32 contiguous t per lane
  const int base = lane * CH;
  int cnt = 0;
  for (int k = 0; k < CH; ++k) {
    int tt = base + k;
    if (tt < len) {
      int pt = pathA[tt];
      int pv = (tt > 0) ? (int)pathA[tt - 1] : -1;
      cnt += ((pt != 0) && (pt != pv)) ? 1 : 0;
    }
  }
  int incl = cnt;
  #pragma unroll
  for (int off = 1; off < 64; off <<= 1) {
    int n = __shfl_up(incl, off, 64);
    if (lane >= off) incl += n;
  }
  const int excl  = incl - cnt;
  const int total = __shfl(incl, 63, 64);

  float* __restrict__ ob = out_tok + (size_t)b * NT;
  int pos = excl;
  for (int k = 0; k < CH; ++k) {
    int tt = base + k;
    if (tt < len) {
      int pt = pathA[tt];
      int pv = (tt > 0) ? (int)pathA[tt - 1] : -1;
      if ((pt != 0) && (pt != pv)) { ob[pos] = (float)pt; ++pos; }
    }
  }
  for (int q = total + lane; q < NT; q += 64) ob[q] = -1.0f;

  if (lane == 0) {
    out_lenA[b] = (float)total;
    out_scr[b]  = s;               // lane 0 == beam 0
  }
}

#undef STEP

// ---------------------------------------------------------------------------
extern "C" void kernel_launch(void* const* d_in, const int* in_sizes, int n_in,
                              void* d_out, int out_size, void* d_ws, size_t ws_size,
                              hipStream_t stream) {
  (void)in_sizes; (void)n_in; (void)out_size; (void)ws_size;
  const float* logits  = (const float*)d_in[0];
  const int*   lengths = (const int*)d_in[1];

  float* out_tok  = (float*)d_out;                 // B*T tokens (as float)
  float* out_lenp = out_tok + NB * NT;             // B out_lens
  float* out_scr  = out_lenp + NB;                 // B best_scores
  float* out_logP = out_scr + NB;                  // B*T*V logP

  float* topPf = (float*)d_ws;                     // 16384*12 f32 = 768 KiB
  int*   topI  = (int*)(topPf + (size_t)NB * NT * NK); // 768 KiB

  lsm_top12_kernel<<<NB * NT, 64, 0, stream>>>(logits, out_logP, topPf, topI);
  beam_kernel<<<NB, 64, 0, stream>>>(topPf, topI, lengths, out_tok, out_lenp, out_scr);
}

// Round 4
// 1334.449 us; speedup vs baseline: 1.2749x; 1.2749x over previous
//
#include <hip/hip_runtime.h>
#include <cmath>

#define NB 8
#define NT 2048
#define NV 4096
#define NK 12          // top-K p values kept per row (candidate margin over 8)

__device__ __forceinline__ void lds_fence() {
  asm volatile("s_waitcnt lgkmcnt(0)" ::: "memory");
}

// ---------------------------------------------------------------------------
// Kernel A v4: whole 4096-wide row held in 64 VGPRs per lane (16 float4) ->
// ONE HBM read + ONE HBM write. M = exact f32 row max; L = logf(f32 sum of
// __expf(x-M), 4 partials). logP = (x - M) - L. Top-12 (value desc, idx asc).
// v4: __launch_bounds__(64,4) caps VGPR<=128 -> 4 waves/SIMD (was 3): lsm is
// Little's-law concurrency-bound (~1KB in flight/wave at 25% duty ~= 2.5TB/s
// observed). Group-guard on INS shrinks the compute phase (same selection:
// INS only acts when v > lv[11], and max4 <= lv[11] implies all 4 no-op).
// ---------------------------------------------------------------------------
__global__ __launch_bounds__(64, 4) void lsm_top12_kernel(
    const float* __restrict__ logits,
    float* __restrict__ out_logP,
    float* __restrict__ topPf,
    int* __restrict__ topI)
{
  const int row  = blockIdx.x;           // b*NT + t
  const int lane = threadIdx.x;          // 0..63
  const float4* __restrict__ x4 = (const float4*)(logits + (size_t)row * NV);

  // ---- single HBM read: 16 independent dwordx4 loads into registers ----
  float4 r[16];
  #pragma unroll
  for (int k = 0; k < 16; ++k) r[k] = x4[lane + (k << 6)];

  // ---- exact f32 row max ----
  float m = -INFINITY;
  #pragma unroll
  for (int k = 0; k < 16; ++k)
    m = fmaxf(m, fmaxf(fmaxf(r[k].x, r[k].y), fmaxf(r[k].z, r[k].w)));
  #pragma unroll
  for (int off = 32; off > 0; off >>= 1) m = fmaxf(m, __shfl_xor(m, off, 64));

  // ---- f32 sum of exp, 4 partials; xor-butterfly keeps bits identical ----
  float a0 = 0.0f, a1 = 0.0f, a2 = 0.0f, a3 = 0.0f;
  #pragma unroll
  for (int k = 0; k < 16; ++k) {
    a0 += __expf(r[k].x - m);
    a1 += __expf(r[k].y - m);
    a2 += __expf(r[k].z - m);
    a3 += __expf(r[k].w - m);
  }
  float accf = (a0 + a1) + (a2 + a3);
  #pragma unroll
  for (int off = 32; off > 0; off >>= 1) accf += __shfl_xor(accf, off, 64);
  const float L32 = logf(accf);

  // ---- logP from registers + store + lane-local top-12 ----
  float lv[NK]; int li[NK];
  #pragma unroll
  for (int z = 0; z < NK; ++z) { lv[z] = -INFINITY; li[z] = 0x7FFFFFFF; }

  // strict > on value keeps earlier (lower) index among equals => stable
#define INS(VAL, IDX)                                                       \
  do {                                                                      \
    float _v = (VAL); int _i = (IDX);                                       \
    if (_v > lv[NK - 1]) {                                                  \
      lv[NK - 1] = _v; li[NK - 1] = _i;                                     \
      for (int z = NK - 1; z > 0; --z)                                      \
        if (lv[z] > lv[z - 1]) {                                            \
          float tv = lv[z]; lv[z] = lv[z - 1]; lv[z - 1] = tv;              \
          int   ti = li[z]; li[z] = li[z - 1]; li[z - 1] = ti;              \
        }                                                                   \
    }                                                                       \
  } while (0)

  float4* __restrict__ orow4 = (float4*)(out_logP + (size_t)row * NV);
  #pragma unroll
  for (int k = 0; k < 16; ++k) {
    const int vb = (lane + (k << 6)) << 2;
    float4 o;
    o.x = (r[k].x - m) - L32;
    o.y = (r[k].y - m) - L32;
    o.z = (r[k].z - m) - L32;
    o.w = (r[k].w - m) - L32;
    orow4[lane + (k << 6)] = o;
    const float g4 = fmaxf(fmaxf(o.x, o.y), fmaxf(o.z, o.w));
    if (g4 > lv[NK - 1]) {               // identical selection, fewer branches
      INS(o.x, vb); INS(o.y, vb + 1); INS(o.z, vb + 2); INS(o.w, vb + 3);
    }
  }
#undef INS

  // ---- wave merge: 12 rounds of butterfly argmax (value desc, idx asc) ----
  float mv = 0.0f; int mi = 0;
  #pragma unroll
  for (int rr = 0; rr < NK; ++rr) {
    float cv = lv[0]; int ci = li[0];
    #pragma unroll
    for (int off = 32; off > 0; off >>= 1) {
      float ov = __shfl_xor(cv, off, 64);
      int   oi = __shfl_xor(ci, off, 64);
      if (ov > cv || (ov == cv && oi < ci)) { cv = ov; ci = oi; }
    }
    if (rr == 0)    { mv = cv; mi = ci; }
    if (lane == rr) { mv = cv; mi = ci; }
    if (lv[0] == cv && li[0] == ci) {   // unique owner pops its head
      for (int z = 0; z < NK - 1; ++z) { lv[z] = lv[z + 1]; li[z] = li[z + 1]; }
      lv[NK - 1] = -INFINITY; li[NK - 1] = 0x7FFFFFFF;
    }
  }
  if (lane < NK) {
    topPf[(size_t)row * NK + lane] = mv;
    topI [(size_t)row * NK + lane] = mi;
  }
}

// ---------------------------------------------------------------------------
// Kernel B v5 = v3 (verified 879us) + L2-warm pass + ~u sign-fold.
// One wave per batch; 31 active lanes hold candidates (i,j), (i+1)(j+1) <= 12
// (margin kept: protects late-t rounding-collision ties). Depth-4 register
// prefetch from global; LDS pipe reserved for ds_permute + tokbp writes.
// ---------------------------------------------------------------------------

#define LOADROW(P, V, R)                                                      \
  do {                                                                        \
    const int _r = (R) < NT ? (R) : (NT - 1);                                 \
    P = Pb[(size_t)_r * NK + j_l];                                            \
    V = Ib[(size_t)_r * NK + j_l];                                            \
  } while (0)

// One beam step at time T. Chain: s -> cand -> key -> rank(31 readlane cmps)
// -> permute -> readlane x8 -> 3-level select -> s. Keys unique => ranks
// unique; lanes 0..7 of `pushed` hold the sorted top-8 candidate scores.
// cand < 0 strictly (logP<0, s<0), so the order-map is cb = ~bits(cand).
#define STEP(T, PV, VV)                                                       \
  do {                                                                        \
    const float cand = s + (PV);            /* single f32 add, matches np */  \
    const unsigned int cb = ~__float_as_uint(cand);                           \
    const unsigned int flat = (unsigned int)((i_l << 12) | (VV));             \
    const unsigned long long key =                                            \
        ((unsigned long long)cb << 15) | (unsigned long long)(0x7FFFu ^ flat);\
    const unsigned int klo = (unsigned int)key;                               \
    const unsigned int khi = (unsigned int)(key >> 32);                       \
    int rank = 0;                                                             \
    _Pragma("unroll")                                                         \
    for (int mm = 0; mm < 31; ++mm) {                                         \
      const unsigned int olo =                                                \
          (unsigned int)__builtin_amdgcn_readlane((int)klo, mm);              \
      const unsigned int ohi =                                                \
          (unsigned int)__builtin_amdgcn_readlane((int)khi, mm);              \
      const unsigned long long ok = ((unsigned long long)ohi << 32) | olo;    \
      rank += (ok > key) ? 1 : 0;                                             \
    }                                                                         \
    const bool win = active && (rank < 8);                                    \
    const int sloti = win ? ((T) * 8 + rank) : (NT * 8 + lane);               \
    tokbp[sloti] = (unsigned short)(((VV) << 3) | i_l);                       \
    const int dst4 = win ? (rank << 2) : park4;                               \
    const int pushed =                                                        \
        __builtin_amdgcn_ds_permute(dst4, __float_as_int(cand));              \
    const float w0 = __uint_as_float((unsigned)__builtin_amdgcn_readlane(pushed, 0)); \
    const float w1 = __uint_as_float((unsigned)__builtin_amdgcn_readlane(pushed, 1)); \
    const float w2 = __uint_as_float((unsigned)__builtin_amdgcn_readlane(pushed, 2)); \
    const float w3 = __uint_as_float((unsigned)__builtin_amdgcn_readlane(pushed, 3)); \
    const float w4 = __uint_as_float((unsigned)__builtin_amdgcn_readlane(pushed, 4)); \
    const float w5 = __uint_as_float((unsigned)__builtin_amdgcn_readlane(pushed, 5)); \
    const float w6 = __uint_as_float((unsigned)__builtin_amdgcn_readlane(pushed, 6)); \
    const float w7 = __uint_as_float((unsigned)__builtin_amdgcn_readlane(pushed, 7)); \
    const float sA_ = b0 ? w1 : w0;                                           \
    const float sB_ = b0 ? w3 : w2;                                           \
    const float sC_ = b0 ? w5 : w4;                                           \
    const float sD_ = b0 ? w7 : w6;                                           \
    const float sE_ = b1 ? sB_ : sA_;                                         \
    const float sF_ = b1 ? sD_ : sC_;                                         \
    s = b2 ? sF_ : sE_;                                                       \
  } while (0)

__global__ __launch_bounds__(64) void beam_kernel(
    const float* __restrict__ topPf,
    const int* __restrict__ topI,
    const int* __restrict__ lengths,
    float* __restrict__ out_tok,
    float* __restrict__ out_lenA,
    float* __restrict__ out_scr)
{
  const int b    = blockIdx.x;
  const int lane = threadIdx.x;

  __shared__ unsigned short tokbp[NT * 8 + 64]; // (v<<3)|bp per (t,rank) + dummy
  __shared__ unsigned short pathA[NT];

  int len = lengths[b];
  if (len < 1) len = 1;
  if (len > NT) len = NT;

  // lane -> (i,j) over all (i+1)(j+1) <= 12  (counts 12,6,4,3,2,2,1,1 = 31)
  int i_l = 0, j_l = 0; bool active = false;
  {
    int c = 0;
    #pragma unroll
    for (int i = 0; i < 8; ++i) {
      const int cnt = 12 / (i + 1);          // floor
      if (lane >= c && lane < c + cnt) { i_l = i; j_l = lane - c; active = true; }
      c += cnt;
    }
  }
  const bool b0 = (i_l & 1) != 0;
  const bool b1 = (i_l & 2) != 0;
  const bool b2 = (i_l & 4) != 0;
  const int  park4 = (32 + (lane & 31)) << 2;   // loser/idle permute dst (bytes)

  const float* __restrict__ Pb = topPf + (size_t)b * NT * NK;
  const int*   __restrict__ Ib = topI  + (size_t)b * NT * NK;

  // ---- warm local (reader-XCD) L2: one pass over this batch's P/I (192 KB).
  // Subsequent j_l-gather loads then hit local L2 (~200cy) instead of L3.
  {
    const float4* __restrict__ gp = (const float4*)Pb;
    const int4*   __restrict__ gi = (const int4*)Ib;
    float fa = 0.0f; int ia = 0;
    #pragma unroll 4
    for (int q = lane; q < NT * NK / 4; q += 64) {
      const float4 v = gp[q]; const int4 w = gi[q];
      fa += (v.x + v.y) + (v.z + v.w);
      ia ^= (w.x ^ w.y) ^ (w.z ^ w.w);
    }
    asm volatile("" :: "v"(fa), "v"(ia));     // keep loads live (no DCE)
  }

  // t = 0: beams = row-0 top-8 (sorted desc, idx-asc ties)
  float s = Pb[i_l];
  if (lane < 8) tokbp[lane] = (unsigned short)(Ib[lane] << 3);   // bp = 0

  // depth-4 register prefetch: set A = rows t..t+3, set B = rows t+4..t+7.
  float pA0, pA1, pA2, pA3, pB0, pB1, pB2, pB3;
  int   vA0, vA1, vA2, vA3, vB0, vB1, vB2, vB3;
  LOADROW(pA0, vA0, 1); LOADROW(pA1, vA1, 2);
  LOADROW(pA2, vA2, 3); LOADROW(pA3, vA3, 4);
  LOADROW(pB0, vB0, 5); LOADROW(pB1, vB1, 6);
  LOADROW(pB2, vB2, 7); LOADROW(pB3, vB3, 8);

  int t = 1;
  for (; t + 7 < len; t += 8) {
    STEP(t,     pA0, vA0);
    STEP(t + 1, pA1, vA1);
    STEP(t + 2, pA2, vA2);
    STEP(t + 3, pA3, vA3);
    LOADROW(pA0, vA0, t + 8);  LOADROW(pA1, vA1, t + 9);
    LOADROW(pA2, vA2, t + 10); LOADROW(pA3, vA3, t + 11);
    STEP(t + 4, pB0, vB0);
    STEP(t + 5, pB1, vB1);
    STEP(t + 6, pB2, vB2);
    STEP(t + 7, pB3, vB3);
    LOADROW(pB0, vB0, t + 12); LOADROW(pB1, vB1, t + 13);
    LOADROW(pB2, vB2, t + 14); LOADROW(pB3, vB3, t + 15);
  }
  // tail: up to 7 remaining steps; set A = rows t..t+3, set B = t+4..t+7
  if (t     < len) STEP(t,     pA0, vA0);
  if (t + 1 < len) STEP(t + 1, pA1, vA1);
  if (t + 2 < len) STEP(t + 2, pA2, vA2);
  if (t + 3 < len) STEP(t + 3, pA3, vA3);
  if (t + 4 < len) STEP(t + 4, pB0, vB0);
  if (t + 5 < len) STEP(t + 5, pB1, vB1);
  if (t + 6 < len) STEP(t + 6, pB2, vB2);

  // ---- backtrace best beam (beam 0), b128 row loads staged 4 deep ----
  lds_fence();
  if (lane == 0) {
    const uint4* __restrict__ rows = (const uint4*)tokbp;  // 8 u16 per row
#define EXT(R)                                                                \
    do {                                                                      \
      const unsigned long long half = (beam < 4)                              \
          ? (((unsigned long long)(R).y << 32) | (R).x)                       \
          : (((unsigned long long)(R).w << 32) | (R).z);                      \
      const int e = (int)((half >> ((beam & 3) << 4)) & 0xFFFFu);             \
      pathA[bt] = (unsigned short)(e >> 3);                                   \
      beam = e & 7;                                                           \
      --bt;                                                                   \
    } while (0)
    int beam = 0;
    int bt = len - 1;
    uint4 r0 = rows[bt];
    uint4 r1 = rows[bt >= 1 ? bt - 1 : 0];
    uint4 r2 = rows[bt >= 2 ? bt - 2 : 0];
    uint4 r3 = rows[bt >= 3 ? bt - 3 : 0];
    while (bt >= 7) {
      const uint4 n0 = rows[bt - 4], n1 = rows[bt - 5];
      const uint4 n2 = rows[bt - 6], n3 = rows[bt - 7];
      EXT(r0); EXT(r1); EXT(r2); EXT(r3);
      r0 = n0; r1 = n1; r2 = n2; r3 = n3;
    }
    while (bt >= 0) { const uint4 rr = rows[bt]; EXT(rr); }
#undef EXT
  }
  lds_fence();

  // ---- CTC collapse: drop blanks & consecutive repeats, t < len ----
  const int CH = NT / 64;          // 32 contiguous t per lane
  const int base = lane * CH;
  int cnt = 0;
  for (int k = 0; k < CH; ++k) {
    int tt = base + k;
    if (tt < len) {
      int pt = pathA[tt];
      int pv = (tt > 0) ? (int)pathA[tt - 1] : -1;
      cnt += ((pt != 0) && (pt != pv)) ? 1 : 0;
    }
  }
  int incl = cnt;
  #pragma unroll
  for (int off = 1; off < 64; off <<= 1) {
    int n = __shfl_up(incl, off, 64);
    if (lane >= off) incl += n;
  }
  const int excl  = incl - cnt;
  const int total = __shfl(incl, 63, 64);

  float* __restrict__ ob = out_tok + (size_t)b * NT;
  int pos = excl;
  for (int k = 0; k < CH; ++k) {
    int tt = base + k;
    if (tt < len) {
      int pt = pathA[tt];
      int pv = (tt > 0) ? (int)pathA[tt - 1] : -1;
      if ((pt != 0) && (pt != pv)) { ob[pos] = (float)pt; ++pos; }
    }
  }
  for (int q = total + lane; q < NT; q += 64) ob[q] = -1.0f;

  if (lane == 0) {
    out_lenA[b] = (float)total;
    out_scr[b]  = s;               // lane 0 == beam 0
  }
}

#undef STEP
#undef LOADROW

// ---------------------------------------------------------------------------
extern "C" void kernel_launch(void* const* d_in, const int* in_sizes, int n_in,
                              void* d_out, int out_size, void* d_ws, size_t ws_size,
                              hipStream_t stream) {
  (void)in_sizes; (void)n_in; (void)out_size; (void)ws_size;
  const float* logits  = (const float*)d_in[0];
  const int*   lengths = (const int*)d_in[1];

  float* out_tok  = (float*)d_out;                 // B*T tokens (as float)
  float* out_lenp = out_tok + NB * NT;             // B out_lens
  float* out_scr  = out_lenp + NB;                 // B best_scores
  float* out_logP = out_scr + NB;                  // B*T*V logP

  float* topPf = (float*)d_ws;                     // 16384*12 f32 = 768 KiB
  int*   topI  = (int*)(topPf + (size_t)NB * NT * NK); // 768 KiB

  lsm_top12_kernel<<<NB * NT, 64, 0, stream>>>(logits, out_logP, topPf, topI);
  beam_kernel<<<NB, 64, 0, stream>>>(topPf, topI, lengths, out_tok, out_lenp, out_scr);
}